// Round 1
// baseline (124.829 us; speedup 1.0000x reference)
//
#include <hip/hip_runtime.h>

// ws layout (floats):
// ws[0] = sum(part1*part2*part3)  (to be negated)
// ws[1] = num_pos
// ws[2] = count(pred > 0.3)
// ws[3] = wh smooth-l1 sum
// ws[4] = off smooth-l1 sum
// ws[5] = mask sum counted per-channel (i.e. 2 * sum(mask))

__device__ __forceinline__ void block_reduce_atomic3(float a, float b, float c,
                                                     float* ws, int i0, int i1, int i2) {
    // wave(64)-level shuffle reduce
    #pragma unroll
    for (int off = 32; off > 0; off >>= 1) {
        a += __shfl_down(a, off, 64);
        b += __shfl_down(b, off, 64);
        c += __shfl_down(c, off, 64);
    }
    __shared__ float sa[8], sb[8], sc[8];
    int lane = threadIdx.x & 63;
    int wave = threadIdx.x >> 6;
    if (lane == 0) { sa[wave] = a; sb[wave] = b; sc[wave] = c; }
    __syncthreads();
    if (threadIdx.x == 0) {
        int nw = (blockDim.x + 63) >> 6;
        float ta = 0.f, tb = 0.f, tc = 0.f;
        for (int w = 0; w < nw; ++w) { ta += sa[w]; tb += sb[w]; tc += sc[w]; }
        atomicAdd(&ws[i0], ta);
        atomicAdd(&ws[i1], tb);
        atomicAdd(&ws[i2], tc);
    }
}

__device__ __forceinline__ void hm_elem(float x, float gt,
                                        float& s_loss, float& s_pos, float& s_cnt) {
    float e = __expf(-x);
    float p = 1.0f / (1.0f + e);
    p = fminf(fmaxf(p, 1e-4f), 1.0f - 1e-4f);

    float pos = (gt == 1.0f) ? 1.0f : 0.0f;
    float neg = (gt < 1.0f)  ? 1.0f : 0.0f;

    float a  = pos + (2.0f * neg - 1.0f) * p;    // part1 base
    float b  = neg + (2.0f * pos - 1.0f) * gt;   // part2 base
    float p1 = a * a;
    float b2 = b * b;
    float p2 = b2 * b2;
    float p3 = __logf(neg + (2.0f * pos - 1.0f) * p);

    s_loss += p1 * p2 * p3;
    s_pos  += pos;
    s_cnt  += (p > 0.3f) ? 1.0f : 0.0f;
}

__global__ void __launch_bounds__(256)
hm_loss_kernel(const float* __restrict__ hm_pred,
               const float* __restrict__ hm_gt,
               float* __restrict__ ws, long long N) {
    long long tid = (long long)blockIdx.x * blockDim.x + threadIdx.x;
    long long nthreads = (long long)gridDim.x * blockDim.x;
    long long N4 = N >> 2;

    float s_loss = 0.f, s_pos = 0.f, s_cnt = 0.f;
    const float4* p4 = (const float4*)hm_pred;
    const float4* g4 = (const float4*)hm_gt;

    for (long long i = tid; i < N4; i += nthreads) {
        float4 xp = p4[i];
        float4 xg = g4[i];
        hm_elem(xp.x, xg.x, s_loss, s_pos, s_cnt);
        hm_elem(xp.y, xg.y, s_loss, s_pos, s_cnt);
        hm_elem(xp.z, xg.z, s_loss, s_pos, s_cnt);
        hm_elem(xp.w, xg.w, s_loss, s_pos, s_cnt);
    }
    // scalar tail (N % 4)
    for (long long i = (N4 << 2) + tid; i < N; i += nthreads) {
        hm_elem(hm_pred[i], hm_gt[i], s_loss, s_pos, s_cnt);
    }

    block_reduce_atomic3(s_loss, s_pos, s_cnt, ws, 0, 1, 2);
}

__device__ __forceinline__ float smooth_l1(float d) {
    float ad = fabsf(d);
    return (ad < 1.0f) ? 0.5f * d * d : ad - 0.5f;
}

__global__ void __launch_bounds__(256)
reg_loss_kernel(const float* __restrict__ wh_pred,  const float* __restrict__ wh_gt,
                const float* __restrict__ off_pred, const float* __restrict__ off_gt,
                const int* __restrict__ mask, const int* __restrict__ ind,
                float* __restrict__ ws, int BK, int K, int HW) {
    int t = blockIdx.x * blockDim.x + threadIdx.x;
    int nt = gridDim.x * blockDim.x;
    float s_wh = 0.f, s_off = 0.f, s_m = 0.f;

    for (int i = t; i < BK; i += nt) {
        int b   = i / K;
        float m = (float)mask[i];
        int idx = ind[i];
        const float* wb = wh_pred  + (size_t)b * 2 * HW;
        const float* ob = off_pred + (size_t)b * 2 * HW;
        #pragma unroll
        for (int c = 0; c < 2; ++c) {
            float gw = wb[(size_t)c * HW + idx];
            float tw = wh_gt[(size_t)i * 2 + c];
            s_wh += smooth_l1(gw * m - tw * m);

            float go = ob[(size_t)c * HW + idx];
            float to = off_gt[(size_t)i * 2 + c];
            s_off += smooth_l1(go * m - to * m);
        }
        s_m += 2.0f * m;   // mask broadcast over C=2 channels
    }

    block_reduce_atomic3(s_wh, s_off, s_m, ws, 3, 4, 5);
}

__global__ void finalize_kernel(const float* __restrict__ ws, float* __restrict__ out) {
    float loss_sum = -ws[0];
    float num_pos  = ws[1];
    float fallback = fmaxf(ws[2], 1.0f);
    float denom    = (num_pos == 0.0f) ? fallback : num_pos;
    float hm_loss  = loss_sum / denom;

    float md       = ws[5] + 1e-4f;
    float wh_loss  = ws[3] / md;
    float off_loss = ws[4] / md;

    out[0] = hm_loss;
    out[1] = wh_loss;
    out[2] = off_loss;
    out[3] = 1.0f * hm_loss + 0.1f * wh_loss + 1.0f * off_loss;
}

extern "C" void kernel_launch(void* const* d_in, const int* in_sizes, int n_in,
                              void* d_out, int out_size, void* d_ws, size_t ws_size,
                              hipStream_t stream) {
    const float* hm_pred  = (const float*)d_in[0];
    const float* hm_gt    = (const float*)d_in[1];
    const float* wh_pred  = (const float*)d_in[2];
    const float* wh_gt    = (const float*)d_in[3];
    const float* off_pred = (const float*)d_in[4];
    const float* off_gt   = (const float*)d_in[5];
    const int*   mask     = (const int*)d_in[6];
    const int*   ind      = (const int*)d_in[7];
    float*       out      = (float*)d_out;
    float*       ws       = (float*)d_ws;

    long long N  = in_sizes[0];          // B*C*H*W
    int       BK = in_sizes[6];          // B*K
    const int K  = 128;                  // per reference setup
    int       B  = BK / K;
    int       HW = in_sizes[2] / (2 * B);

    hipMemsetAsync(d_ws, 0, 8 * sizeof(float), stream);

    hm_loss_kernel<<<2048, 256, 0, stream>>>(hm_pred, hm_gt, ws, N);
    reg_loss_kernel<<<64, 256, 0, stream>>>(wh_pred, wh_gt, off_pred, off_gt,
                                            mask, ind, ws, BK, K, HW);
    finalize_kernel<<<1, 1, 0, stream>>>(ws, out);
}